// Round 6
// baseline (48.126 us; speedup 1.0000x reference)
//
#include <hip/hip_runtime.h>
#include <hip/hip_bf16.h>

#define N_NODES 4096
#define IN_FEAT 128
#define OUT_FEAT 64
#define NHEAD 4
#define HID 256           // NHEAD * OUT_FEAT
#define NEG_SLOPE 0.2f
#define MAXC 256          // per-node neighbor cap (expected max degree ~75)
#define GEMM_BLOCKS 256   // 64 row-blocks x 4 col-blocks (64x64 output tiles)

typedef float f4 __attribute__((ext_vector_type(4)));

// ---------------------------------------------------------------------------
// Kernel S: adj scan, ONE ROW PER WAVE, zero LDS, nontemporal streaming loads.
// 1024 blocks x 256 thr (4 waves). Each lane: 16 f4 nt-loads (16KB/wave
// in flight), u64 bit mask, wave prefix, scatter compacted list.
// ---------------------------------------------------------------------------
__global__ __launch_bounds__(256) void k_scan(
    const float* __restrict__ adj,
    unsigned short* __restrict__ nbrs, int* __restrict__ deg)
{
    const int t = threadIdx.x;
    const int lane = t & 63;
    const int wv = t >> 6;
    const int i = blockIdx.x * 4 + wv;                 // row 0..4095

    const f4* arow = reinterpret_cast<const f4*>(adj + (size_t)i * N_NODES);
    f4 v[16];
    #pragma unroll
    for (int u = 0; u < 16; ++u)
        v[u] = __builtin_nontemporal_load(&arow[u * 64 + lane]);

    unsigned long long m = 0ull;
    #pragma unroll
    for (int u = 0; u < 16; ++u) {
        const int jb = u * 256 + lane * 4;
        if (v[u][0] != 0.f || (jb + 0) == i) m |= 1ull << (u * 4 + 0);
        if (v[u][1] != 0.f || (jb + 1) == i) m |= 1ull << (u * 4 + 1);
        if (v[u][2] != 0.f || (jb + 2) == i) m |= 1ull << (u * 4 + 2);
        if (v[u][3] != 0.f || (jb + 3) == i) m |= 1ull << (u * 4 + 3);
    }
    const int cnt = __popcll(m);

    int incl = cnt;                                    // wave inclusive prefix
    #pragma unroll
    for (int d = 1; d < 64; d <<= 1) {
        int u2 = __shfl_up(incl, d, 64);
        if (lane >= d) incl += u2;
    }
    int off = incl - cnt;
    if (lane == 63) deg[i] = (incl < MAXC) ? incl : MAXC;

    unsigned short* nl = nbrs + (size_t)i * MAXC;
    unsigned long long mm = m;
    while (mm) {
        const int b = __ffsll(mm) - 1;
        mm &= mm - 1;
        const int j = ((b >> 2) * 256) + lane * 4 + (b & 3);
        if (off < MAXC) nl[off] = (unsigned short)j;
        ++off;
    }
}

// ---------------------------------------------------------------------------
// Kernel G: register-tiled GEMM h = x@W (64x64 tile, 4x4/thread) + fused
// attn_src/tgt reductions. 256 blocks.
// ---------------------------------------------------------------------------
__global__ __launch_bounds__(256) void k_gemm(
    const float* __restrict__ x, const float* __restrict__ W,
    const float* __restrict__ a, float* __restrict__ h,
    float* __restrict__ attn_src, float* __restrict__ attn_tgt)
{
    __shared__ f4 xs4[64][32];        // x tile, XOR-swizzled along kq (32KB)
    __shared__ float red_s[4][64];
    __shared__ float red_t[4][64];

    const int t = threadIdx.x;
    const int rb = blockIdx.x >> 2;        // row block 0..63
    const int cb = blockIdx.x & 3;         // col block == head
    const int row0 = rb * 64;
    const int tc4 = (t >> 4) * 4;
    const int c0 = cb * 64 + tc4;
    const int tr = t & 15;
    const int wv = t >> 6;

    {
        const f4* xg = reinterpret_cast<const f4*>(x) + (size_t)row0 * 32;
        const int kq = t & 31;
        #pragma unroll
        for (int it = 0; it < 8; ++it) {
            const int r = it * 8 + (t >> 5);
            xs4[r][kq ^ ((r >> 2) & 7)] = xg[r * 32 + kq];
        }
    }
    __syncthreads();

    f4 acc[4] = {};
    for (int kq = 0; kq < 32; ++kq) {
        f4 wvv[4];
        #pragma unroll
        for (int kk = 0; kk < 4; ++kk)
            wvv[kk] = *reinterpret_cast<const f4*>(W + (kq * 4 + kk) * HID + c0);
        f4 xv[4];
        #pragma unroll
        for (int j = 0; j < 4; ++j)
            xv[j] = xs4[tr * 4 + j][kq ^ (tr & 7)];
        #pragma unroll
        for (int kk = 0; kk < 4; ++kk)
            #pragma unroll
            for (int j = 0; j < 4; ++j)
                acc[j] += xv[j][kk] * wvv[kk];
    }

    #pragma unroll
    for (int j = 0; j < 4; ++j) {
        const int row = row0 + tr * 4 + j;
        *reinterpret_cast<f4*>(h + (size_t)row * HID + c0) = acc[j];
    }

    const f4 asv = *reinterpret_cast<const f4*>(a + cb * 2 * OUT_FEAT + tc4);
    const f4 atv = *reinterpret_cast<const f4*>(a + cb * 2 * OUT_FEAT + OUT_FEAT + tc4);
    #pragma unroll
    for (int j = 0; j < 4; ++j) {
        float s = acc[j][0] * asv[0] + acc[j][1] * asv[1]
                + acc[j][2] * asv[2] + acc[j][3] * asv[3];
        float g = acc[j][0] * atv[0] + acc[j][1] * atv[1]
                + acc[j][2] * atv[2] + acc[j][3] * atv[3];
        s += __shfl_xor(s, 16, 64); s += __shfl_xor(s, 32, 64);
        g += __shfl_xor(g, 16, 64); g += __shfl_xor(g, 32, 64);
        if (((t >> 4) & 3) == 0) {
            red_s[wv][tr * 4 + j] = s;
            red_t[wv][tr * 4 + j] = g;
        }
    }
    __syncthreads();
    if (t < 64) {
        const float s = red_s[0][t] + red_s[1][t] + red_s[2][t] + red_s[3][t];
        const float g = red_t[0][t] + red_t[1][t] + red_t[2][t] + red_t[3][t];
        attn_src[(row0 + t) * NHEAD + cb] = s;
        attn_tgt[(row0 + t) * NHEAD + cb] = g;
    }
}

// ---------------------------------------------------------------------------
// Kernel A: per node i — softmax over neighbor list + aggregation
// (4 neighbors / iteration, float4 per lane). Wave wv owns head wv.
// ---------------------------------------------------------------------------
__global__ __launch_bounds__(256) void k_agg(
    const unsigned short* __restrict__ nbrs, const int* __restrict__ deg,
    const float* __restrict__ h, const float* __restrict__ attn_src,
    const float* __restrict__ attn_tgt, float* __restrict__ out)
{
    __shared__ float p[NHEAD][MAXC];
    __shared__ unsigned short nl[MAXC];

    const int i = blockIdx.x;
    const int t = threadIdx.x;
    const int lane = t & 63;
    const int head = t >> 6;

    const int d = deg[i];
    nl[t] = (t < d) ? nbrs[(size_t)i * MAXC + t] : (unsigned short)0;
    __syncthreads();

    const float srcv = attn_src[i * NHEAD + head];
    const int rnd = (d + 3) & ~3;
    float lmax = -1e30f;
    for (int idx = lane; idx < rnd; idx += 64) {
        if (idx < d) {
            float e = srcv + attn_tgt[nl[idx] * NHEAD + head];
            e = (e > 0.f) ? e : NEG_SLOPE * e;
            p[head][idx] = e;
            lmax = fmaxf(lmax, e);
        } else {
            p[head][idx] = 0.f;
        }
    }
    #pragma unroll
    for (int s = 32; s; s >>= 1) lmax = fmaxf(lmax, __shfl_xor(lmax, s, 64));
    float ssum = 0.f;
    for (int idx = lane; idx < d; idx += 64) {
        float pe = __expf(p[head][idx] - lmax);
        p[head][idx] = pe;
        ssum += pe;
    }
    #pragma unroll
    for (int s = 32; s; s >>= 1) ssum += __shfl_xor(ssum, s, 64);
    const float inv = 1.0f / ssum;

    const int g  = lane >> 4;
    const int f4i = lane & 15;
    const float* hbase = h + head * OUT_FEAT + f4i * 4;
    float4 acc = {0.f, 0.f, 0.f, 0.f};
    for (int idx4 = 0; idx4 < d; idx4 += 4) {
        const int j   = nl[idx4 + g];
        const float pw = p[head][idx4 + g];
        const float4 hv = *reinterpret_cast<const float4*>(hbase + (size_t)j * HID);
        acc.x += pw * hv.x; acc.y += pw * hv.y;
        acc.z += pw * hv.z; acc.w += pw * hv.w;
    }
    #pragma unroll
    for (int s = 16; s <= 32; s <<= 1) {
        acc.x += __shfl_xor(acc.x, s, 64);
        acc.y += __shfl_xor(acc.y, s, 64);
        acc.z += __shfl_xor(acc.z, s, 64);
        acc.w += __shfl_xor(acc.w, s, 64);
    }
    if (g == 0) {
        float4 o = {acc.x * inv, acc.y * inv, acc.z * inv, acc.w * inv};
        *reinterpret_cast<float4*>(out + (size_t)i * HID + head * OUT_FEAT + f4i * 4) = o;
    }
}

// ---------------------------------------------------------------------------
extern "C" void kernel_launch(void* const* d_in, const int* in_sizes, int n_in,
                              void* d_out, int out_size, void* d_ws, size_t ws_size,
                              hipStream_t stream)
{
    const float* x   = (const float*)d_in[0];   // (4096,128)
    const float* adj = (const float*)d_in[1];   // (4096,4096)
    const float* W   = (const float*)d_in[2];   // (128,256)
    const float* a   = (const float*)d_in[3];   // (4,128)
    float* out = (float*)d_out;                 // (4096,256)

    char* ws = (char*)d_ws;
    float* h         = (float*)ws;                                  // 4 MB
    float* attn_src  = (float*)(ws + (size_t)N_NODES * HID * 4);    // 64 KB
    float* attn_tgt  = attn_src + (size_t)N_NODES * NHEAD;          // 64 KB
    unsigned short* nbrs = (unsigned short*)(attn_tgt + (size_t)N_NODES * NHEAD); // 2 MB
    int* deg         = (int*)(nbrs + (size_t)N_NODES * MAXC);       // 16 KB

    k_scan<<<N_NODES / 4, 256, 0, stream>>>(adj, nbrs, deg);
    k_gemm<<<GEMM_BLOCKS, 256, 0, stream>>>(x, W, a, h, attn_src, attn_tgt);
    k_agg<<<N_NODES, 256, 0, stream>>>(nbrs, deg, h, attn_src, attn_tgt, out);
}

// Round 7
// 38.542 us; speedup vs baseline: 1.2487x; 1.2487x over previous
//
#include <hip/hip_runtime.h>

#define N_NODES 4096
#define IN_FEAT 128
#define OUT_FEAT 64
#define NHEAD 4
#define HID 256           // NHEAD * OUT_FEAT
#define NEG_SLOPE 0.2f
#define MAXC 256          // per-node neighbor cap (expected max degree ~75)
#define GEMM_BLOCKS 256   // 64 row-blocks x 4 col-blocks (64x64 output tiles)
#define STREAM_BLOCKS 512
#define STREAM_THREADS (STREAM_BLOCKS * 256)   // 131072
#define TOT_F4 (N_NODES * (N_NODES / 4))       // 4194304 float4's in adj
#define OUTER (TOT_F4 / STREAM_THREADS / 8)    // 4 outer iters x 8-deep batch

typedef float f4 __attribute__((ext_vector_type(4)));

// ---------------------------------------------------------------------------
// Kernel P (heterogeneous):
//  blocks 0..255   : register-tiled GEMM h=x@W (64x64 tile) + attn reductions
//  blocks 256..767 : PERSISTENT grid-stride adj->bitmap compress (m13 shape):
//                    per iter, 8 batched f4 loads -> 8 nibble bytes, fully
//                    coalesced, no divergence, no LDS, waves live to the end.
// ---------------------------------------------------------------------------
__global__ __launch_bounds__(256) void k_prep(
    const float* __restrict__ x, const float* __restrict__ adj,
    const float* __restrict__ W, const float* __restrict__ a,
    float* __restrict__ h, float* __restrict__ attn_src,
    float* __restrict__ attn_tgt, unsigned char* __restrict__ bitmap)
{
    __shared__ f4 xs4[64][32];        // x tile, XOR-swizzled along kq (32KB)
    __shared__ float red_s[4][64];
    __shared__ float red_t[4][64];

    const int t = threadIdx.x;

    if (blockIdx.x < GEMM_BLOCKS) {
        const int rb = blockIdx.x >> 2;        // row block 0..63
        const int cb = blockIdx.x & 3;         // col block == head
        const int row0 = rb * 64;
        const int tc4 = (t >> 4) * 4;
        const int c0 = cb * 64 + tc4;
        const int tr = t & 15;
        const int wv = t >> 6;

        {
            const f4* xg = reinterpret_cast<const f4*>(x) + (size_t)row0 * 32;
            const int kq = t & 31;
            #pragma unroll
            for (int it = 0; it < 8; ++it) {
                const int r = it * 8 + (t >> 5);
                xs4[r][kq ^ ((r >> 2) & 7)] = xg[r * 32 + kq];
            }
        }
        __syncthreads();

        f4 acc[4] = {};
        for (int kq = 0; kq < 32; ++kq) {
            f4 wvv[4];
            #pragma unroll
            for (int kk = 0; kk < 4; ++kk)
                wvv[kk] = *reinterpret_cast<const f4*>(W + (kq * 4 + kk) * HID + c0);
            f4 xv[4];
            #pragma unroll
            for (int j = 0; j < 4; ++j)
                xv[j] = xs4[tr * 4 + j][kq ^ (tr & 7)];
            #pragma unroll
            for (int kk = 0; kk < 4; ++kk)
                #pragma unroll
                for (int j = 0; j < 4; ++j)
                    acc[j] += xv[j][kk] * wvv[kk];
        }

        #pragma unroll
        for (int j = 0; j < 4; ++j) {
            const int row = row0 + tr * 4 + j;
            *reinterpret_cast<f4*>(h + (size_t)row * HID + c0) = acc[j];
        }

        const f4 asv = *reinterpret_cast<const f4*>(a + cb * 2 * OUT_FEAT + tc4);
        const f4 atv = *reinterpret_cast<const f4*>(a + cb * 2 * OUT_FEAT + OUT_FEAT + tc4);
        #pragma unroll
        for (int j = 0; j < 4; ++j) {
            float s = acc[j][0] * asv[0] + acc[j][1] * asv[1]
                    + acc[j][2] * asv[2] + acc[j][3] * asv[3];
            float g = acc[j][0] * atv[0] + acc[j][1] * atv[1]
                    + acc[j][2] * atv[2] + acc[j][3] * atv[3];
            s += __shfl_xor(s, 16, 64); s += __shfl_xor(s, 32, 64);
            g += __shfl_xor(g, 16, 64); g += __shfl_xor(g, 32, 64);
            if (((t >> 4) & 3) == 0) {
                red_s[wv][tr * 4 + j] = s;
                red_t[wv][tr * 4 + j] = g;
            }
        }
        __syncthreads();
        if (t < 64) {
            const float s = red_s[0][t] + red_s[1][t] + red_s[2][t] + red_s[3][t];
            const float g = red_t[0][t] + red_t[1][t] + red_t[2][t] + red_t[3][t];
            attn_src[(row0 + t) * NHEAD + cb] = s;
            attn_tgt[(row0 + t) * NHEAD + cb] = g;
        }
    } else {
        // ---- persistent adj -> bitmap stream ----
        const int g = (blockIdx.x - GEMM_BLOCKS) * 256 + t;   // 0..131071
        const f4* src = reinterpret_cast<const f4*>(adj);
        for (int r = 0; r < OUTER; ++r) {
            f4 v[8];
            #pragma unroll
            for (int u = 0; u < 8; ++u)
                v[u] = src[(size_t)(r * 8 + u) * STREAM_THREADS + g];
            #pragma unroll
            for (int u = 0; u < 8; ++u) {
                const unsigned nib = (v[u][0] != 0.f ? 1u : 0u)
                                   | (v[u][1] != 0.f ? 2u : 0u)
                                   | (v[u][2] != 0.f ? 4u : 0u)
                                   | (v[u][3] != 0.f ? 8u : 0u);
                bitmap[(size_t)(r * 8 + u) * STREAM_THREADS + g] = (unsigned char)nib;
            }
        }
    }
}

// ---------------------------------------------------------------------------
// Kernel A: per node i — wave 0 expands the row's 1KB bitmap into a compacted
// LDS neighbor list (nibble-pack -> u64 mask -> prefix -> scatter, + self
// loop), then per-head softmax + aggregation as before.
// ---------------------------------------------------------------------------
__global__ __launch_bounds__(256) void k_agg(
    const unsigned char* __restrict__ bitmap, const float* __restrict__ h,
    const float* __restrict__ attn_src, const float* __restrict__ attn_tgt,
    float* __restrict__ out)
{
    __shared__ float p[NHEAD][MAXC];
    __shared__ unsigned short nl[MAXC];
    __shared__ int sdeg;

    const int i = blockIdx.x;
    const int t = threadIdx.x;
    const int lane = t & 63;
    const int head = t >> 6;

    if (t < 64) {   // wave 0 builds the list
        for (int k = lane; k < MAXC; k += 64) nl[k] = 0;   // pad for agg loop

        const unsigned long long* wrow = reinterpret_cast<const unsigned long long*>(
            bitmap + (size_t)i * (N_NODES / 4));
        unsigned long long w0 = wrow[lane * 2 + 0];        // bytes 0..7  of my 16
        unsigned long long w1 = wrow[lane * 2 + 1];        // bytes 8..15

        // pack 8 nibble-bytes -> 32 bits
        #define PACK(b) ({ unsigned long long _b = (b) & 0x0F0F0F0F0F0F0F0Full; \
            _b = (_b | (_b >> 4))  & 0x00FF00FF00FF00FFull;                      \
            _b = (_b | (_b >> 8))  & 0x0000FFFF0000FFFFull;                      \
            _b = (_b | (_b >> 16)) & 0x00000000FFFFFFFFull; _b; })
        unsigned long long m = PACK(w0) | (PACK(w1) << 32);
        #undef PACK
        if ((i >> 6) == lane) m |= 1ull << (i & 63);       // self loop

        const int cnt = __popcll(m);
        int incl = cnt;
        #pragma unroll
        for (int d2 = 1; d2 < 64; d2 <<= 1) {
            int u2 = __shfl_up(incl, d2, 64);
            if (lane >= d2) incl += u2;
        }
        int off = incl - cnt;
        int total = __shfl(incl, 63, 64);
        if (total > MAXC) total = MAXC;
        if (lane == 0) sdeg = total;
        while (m) {
            const int b = __ffsll(m) - 1;
            m &= m - 1;
            if (off < MAXC) nl[off] = (unsigned short)(lane * 64 + b);
            ++off;
        }
    }
    __syncthreads();
    const int d = sdeg;

    // ---- softmax (wave-local per head) ----
    const float srcv = attn_src[i * NHEAD + head];
    const int rnd = (d + 3) & ~3;
    float lmax = -1e30f;
    for (int idx = lane; idx < rnd; idx += 64) {
        if (idx < d) {
            float e = srcv + attn_tgt[nl[idx] * NHEAD + head];
            e = (e > 0.f) ? e : NEG_SLOPE * e;
            p[head][idx] = e;
            lmax = fmaxf(lmax, e);
        } else {
            p[head][idx] = 0.f;
        }
    }
    #pragma unroll
    for (int s = 32; s; s >>= 1) lmax = fmaxf(lmax, __shfl_xor(lmax, s, 64));
    float ssum = 0.f;
    for (int idx = lane; idx < d; idx += 64) {
        float pe = __expf(p[head][idx] - lmax);
        p[head][idx] = pe;
        ssum += pe;
    }
    #pragma unroll
    for (int s = 32; s; s >>= 1) ssum += __shfl_xor(ssum, s, 64);
    const float inv = 1.0f / ssum;   // d >= 1 always (self loop)

    // ---- aggregation: 4 neighbors per iteration ----
    const int g  = lane >> 4;
    const int f4i = lane & 15;
    const float* hbase = h + head * OUT_FEAT + f4i * 4;
    float4 acc = {0.f, 0.f, 0.f, 0.f};
    for (int idx4 = 0; idx4 < d; idx4 += 4) {
        const int j   = nl[idx4 + g];
        const float pw = p[head][idx4 + g];
        const float4 hv = *reinterpret_cast<const float4*>(hbase + (size_t)j * HID);
        acc.x += pw * hv.x; acc.y += pw * hv.y;
        acc.z += pw * hv.z; acc.w += pw * hv.w;
    }
    #pragma unroll
    for (int s = 16; s <= 32; s <<= 1) {
        acc.x += __shfl_xor(acc.x, s, 64);
        acc.y += __shfl_xor(acc.y, s, 64);
        acc.z += __shfl_xor(acc.z, s, 64);
        acc.w += __shfl_xor(acc.w, s, 64);
    }
    if (g == 0) {
        float4 o = {acc.x * inv, acc.y * inv, acc.z * inv, acc.w * inv};
        *reinterpret_cast<float4*>(out + (size_t)i * HID + head * OUT_FEAT + f4i * 4) = o;
    }
}

// ---------------------------------------------------------------------------
extern "C" void kernel_launch(void* const* d_in, const int* in_sizes, int n_in,
                              void* d_out, int out_size, void* d_ws, size_t ws_size,
                              hipStream_t stream)
{
    const float* x   = (const float*)d_in[0];   // (4096,128)
    const float* adj = (const float*)d_in[1];   // (4096,4096)
    const float* W   = (const float*)d_in[2];   // (128,256)
    const float* a   = (const float*)d_in[3];   // (4,128)
    float* out = (float*)d_out;                 // (4096,256)

    char* ws = (char*)d_ws;
    float* h         = (float*)ws;                                   // 4 MB
    float* attn_src  = (float*)(ws + (size_t)N_NODES * HID * 4);     // 64 KB
    float* attn_tgt  = attn_src + (size_t)N_NODES * NHEAD;           // 64 KB
    unsigned char* bitmap = (unsigned char*)(attn_tgt + (size_t)N_NODES * NHEAD); // 4 MB

    k_prep<<<GEMM_BLOCKS + STREAM_BLOCKS, 256, 0, stream>>>(
        x, adj, W, a, h, attn_src, attn_tgt, bitmap);
    k_agg<<<N_NODES, 256, 0, stream>>>(bitmap, h, attn_src, attn_tgt, out);
}